// Round 9
// baseline (369.339 us; speedup 1.0000x reference)
//
#include <hip/hip_runtime.h>
#include <cstdint>
#include <cstddef>

typedef __bf16 bf16;
typedef __bf16 bf16x8 __attribute__((ext_vector_type(8)));
typedef __bf16 bf16x4 __attribute__((ext_vector_type(4)));
typedef float  f32x4  __attribute__((ext_vector_type(4)));
typedef float  f32x16 __attribute__((ext_vector_type(16)));

#define MFMA16(a, b, c) __builtin_amdgcn_mfma_f32_16x16x32_bf16((a), (b), (c), 0, 0, 0)
#define MFMA32(a, b, c) __builtin_amdgcn_mfma_f32_32x32x16_bf16((a), (b), (c), 0, 0, 0)

static constexpr int BB   = 4;
static constexpr int TT   = 2048;
static constexpr int DM   = 1024;
static constexpr int NH   = 16;
static constexpr int HD   = 64;
static constexpr int TOK  = BB * TT;    // 8192
static constexpr int NQKV = 3 * DM;     // 3072

// async global->LDS, 16B per lane; dst must be wave-uniform base (HW adds lane*16)
__device__ inline void gload16(const void* g, void* l) {
    __builtin_amdgcn_global_load_lds((const __attribute__((address_space(1))) void*)g,
                                     (__attribute__((address_space(3))) void*)l, 16, 0, 0);
}

// XOR-swizzle for [64][128B] row-major LDS tiles: spread each column across 8 slots
__device__ inline int swz(int x) { return x ^ ((x >> 3) & 0x70); }

// ---------------- elementwise f32 -> bf16 ----------------
__global__ void k_cvt(const float* __restrict__ in, bf16* __restrict__ out, int n) {
    int i = (blockIdx.x * blockDim.x + threadIdx.x) * 4;
    if (i >= n) return;
    float4 v = *(const float4*)(in + i);
    bf16x4 o;
    o[0] = (bf16)v.x; o[1] = (bf16)v.y; o[2] = (bf16)v.z; o[3] = (bf16)v.w;
    *(bf16x4*)(out + i) = o;
}

// ---------------- transpose + convert: in f32 [R][C] -> out bf16 [C][R] ----------------
__global__ void k_transpose_cvt(const float* __restrict__ in, bf16* __restrict__ out,
                                int R, int C) {
    __shared__ bf16 tl[64 * 72];
    int tid = threadIdx.x;
    int c0 = blockIdx.x * 64, r0 = blockIdx.y * 64;
#pragma unroll
    for (int rep = 0; rep < 4; rep++) {
        int r = rep * 16 + (tid >> 4);
        int c = (tid & 15) * 4;
        float4 v = *(const float4*)(in + (size_t)(r0 + r) * C + c0 + c);
        tl[r * 72 + c + 0] = (bf16)v.x;
        tl[r * 72 + c + 1] = (bf16)v.y;
        tl[r * 72 + c + 2] = (bf16)v.z;
        tl[r * 72 + c + 3] = (bf16)v.w;
    }
    __syncthreads();
#pragma unroll
    for (int rep = 0; rep < 4; rep++) {
        int cc = rep * 16 + (tid >> 4);
        int rr = (tid & 15) * 4;
        bf16x4 o;
        o[0] = tl[(rr + 0) * 72 + cc];
        o[1] = tl[(rr + 1) * 72 + cc];
        o[2] = tl[(rr + 2) * 72 + cc];
        o[3] = tl[(rr + 3) * 72 + cc];
        *(bf16x4*)(out + (size_t)(c0 + cc) * R + r0 + rr) = o;
    }
}

// ---------------- RoPE cos/sin table ----------------
__global__ void k_rope_tab(float* __restrict__ ct, float* __restrict__ st) {
    int i = blockIdx.x * blockDim.x + threadIdx.x;   // TT*32
    int t = i >> 5, j = i & 31;
    float invf = powf(10000.0f, -(float)j * (1.0f / 32.0f));
    float a = (float)t * invf;
    ct[i] = cosf(a);
    st[i] = sinf(a);
}

// ---------------- GEMM: C[M][N] = A[M][K] @ Bt[N][K]^T, bf16 in, f32 acc ----------------
// m97 structure: global_load_lds width=16, linear [128][64] LDS, 2 barriers/K-step.
// MODE 1: fused-RoPE scatter epilogue -> qbuf/kbuf [B,H,T,64] (roped, Q pre-scaled),
//         vbuf [B,H,64,T] (QKV projection). Each wave's 64 n-cols = one head.
// MODE 2: f32 row-major out (final projection)
template <int MODE>
__global__ __launch_bounds__(256) void k_gemm_bt(
    const bf16* __restrict__ A, const bf16* __restrict__ Bt,
    int M, int N, int K,
    float* __restrict__ outF,
    bf16* __restrict__ qbuf, bf16* __restrict__ kbuf, bf16* __restrict__ vbuf,
    const float* __restrict__ ct, const float* __restrict__ st, float qscale) {
    __shared__ bf16 lA[128 * 64];
    __shared__ bf16 lB[128 * 64];
    int tid = threadIdx.x;
    int l = tid & 63, wid = tid >> 6;
    int wm = wid >> 1, wn = wid & 1;                 // 2x2 waves of 64x64
    int bn = blockIdx.x, bm = blockIdx.y;
    const bf16* Ab = A + (size_t)bm * 128 * K;
    const bf16* Bb = Bt + (size_t)bn * 128 * K;
    int srow = l >> 3, scol = (l & 7) * 8;           // within an 8-row chunk
    f32x4 acc[4][4] = {};
    for (int kt = 0; kt < K; kt += 64) {
        __syncthreads();                             // previous iter's ds_reads done
#pragma unroll
        for (int i = 0; i < 4; i++) {
            int chunk = wid * 4 + i;                 // 16 chunks x 512 elems (8 rows)
            gload16(Ab + (size_t)(chunk * 8 + srow) * K + kt + scol, &lA[chunk * 512]);
            gload16(Bb + (size_t)(chunk * 8 + srow) * K + kt + scol, &lB[chunk * 512]);
        }
        __syncthreads();                             // drains vmcnt (compiler-emitted)
#pragma unroll
        for (int kk = 0; kk < 2; kk++) {
            bf16x8 af[4], bfr[4];
#pragma unroll
            for (int mi = 0; mi < 4; mi++)
                af[mi] = *(const bf16x8*)&lA[(wm * 64 + mi * 16 + (l & 15)) * 64 + kk * 32 + (l >> 4) * 8];
#pragma unroll
            for (int ni = 0; ni < 4; ni++)
                bfr[ni] = *(const bf16x8*)&lB[(wn * 64 + ni * 16 + (l & 15)) * 64 + kk * 32 + (l >> 4) * 8];
#pragma unroll
            for (int mi = 0; mi < 4; mi++)
#pragma unroll
                for (int ni = 0; ni < 4; ni++)
                    acc[mi][ni] = MFMA16(af[mi], bfr[ni], acc[mi][ni]);
        }
    }
    if (MODE == 2) {
#pragma unroll
        for (int mi = 0; mi < 4; mi++) {
            int m0 = bm * 128 + wm * 64 + mi * 16 + ((l >> 4) << 2);
#pragma unroll
            for (int ni = 0; ni < 4; ni++) {
                int n = bn * 128 + wn * 64 + ni * 16 + (l & 15);
#pragma unroll
                for (int rj = 0; rj < 4; rj++)
                    outF[(size_t)(m0 + rj) * N + n] = acc[mi][ni][rj];
            }
        }
    } else {
        int n0 = bn * 128 + wn * 64;                 // wave-uniform; 64-col span = one head
        int sQ = n0 >> 10;
        int h = (n0 & 1023) >> 6;
        if (sQ == 2) {                               // V: pre-transposed [B,H,64,T]
#pragma unroll
            for (int ni = 0; ni < 4; ni++) {
                int d = ni * 16 + (l & 15);
#pragma unroll
                for (int mi = 0; mi < 4; mi++) {
                    int m0 = bm * 128 + wm * 64 + mi * 16 + ((l >> 4) << 2);
                    int b = m0 >> 11, t0 = m0 & 2047;
                    bf16x4 pv;
#pragma unroll
                    for (int rj = 0; rj < 4; rj++) pv[rj] = (bf16)acc[mi][ni][rj];
                    *(bf16x4*)(vbuf + ((size_t)((b * NH + h) * HD + d)) * TT + t0) = pv;
                }
            }
        } else {                                     // Q/K: RoPE in f32, then scatter
            float qs = (sQ == 0) ? qscale : 1.0f;
            bf16* obuf = (sQ == 0) ? qbuf : kbuf;
#pragma unroll
            for (int mi = 0; mi < 4; mi++) {
                int m0 = bm * 128 + wm * 64 + mi * 16 + ((l >> 4) << 2);
                int b = m0 >> 11, t0 = m0 & 2047;
#pragma unroll
                for (int rj = 0; rj < 4; rj++) {
                    int t = t0 + rj;
                    bf16* dst = obuf + ((size_t)(b * NH + h) * TT + t) * HD;
                    const float* crow = ct + t * 32;
                    const float* srow = st + t * 32;
#pragma unroll
                    for (int ni2 = 0; ni2 < 2; ni2++) {
                        int d = ni2 * 16 + (l & 15);
                        float cs = crow[d], sn = srow[d];
                        float a  = acc[mi][ni2][rj];
                        float b2 = acc[mi][ni2 + 2][rj];
                        dst[d]      = (bf16)(qs * (a  * cs - b2 * sn));
                        dst[d + 32] = (bf16)(qs * (b2 * cs + a  * sn));
                    }
                }
            }
        }
    }
}

// ---------------- flash attention, 32x32 MFMA retile ----------------
// Q,K [B*H,T,64] (Q pre-scaled by log2e/sqrt(hd), both roped), Vt [B*H,64,T].
// Block (4 waves) owns a PAIR of 128-row q-strips (15-p, p): 36 kv-units/block.
// Wave w computes q-rows [w*32, w*32+32) of the strip via 32x32x16 MFMAs:
//   QK: A=Q-frag (row=l&31=q, k=(l>>5)*8+e), B=K-frag (col=l&31=kv) -> 8 MFMAs
//   C layout: col=l&31, row=(reg&3)+8*(reg>>2)+4*(l>>5)   [m74/m101]
// K tiles staged in LDS (dbuf, DMA, swizzled); V read DIRECT from global
// (L2-resident via XCD remap; staging L2-fit data is pure overhead).
// Fixed-shift softmax: acc init -16, exp2, no max/shuffles; denom via ones-MFMA.
// LDS 33.8KB -> 4 blocks/CU, all 1024 blocks resident (no straggler tail).
__global__ __launch_bounds__(256, 4) void k_attn(
    const bf16* __restrict__ Q, const bf16* __restrict__ K,
    const bf16* __restrict__ Vt, bf16* __restrict__ O) {
    __shared__ bf16 lK[2][4096];    // [64 kv][64 d] swizzled
    __shared__ bf16 lP[128 * 68];   // per-wave-private 32-row stripes, pad->136B stride
    int tid = threadIdx.x;
    int l = tid & 63, w = tid >> 6;
    // XCD-aware remap: same-bh blocks share an XCD (keeps K/V L2-resident)
    int flat = blockIdx.x + (blockIdx.y << 4);       // grid (16,64), x fastest
    int xcd = flat & 7, rank = flat >> 3;            // dispatcher round-robins id%8
    int bh = xcd * 8 + (rank >> 4);                  // 8 bh per XCD, bijective
    int p = rank & 15;                               // pair index 0..15
    const char* KbB = (const char*)(K + (size_t)bh * TT * HD);
    const bf16* Vb = Vt + (size_t)bh * HD * TT;
    int b = bh >> 4, h = bh & 15;

    bf16x8 ones;
#pragma unroll
    for (int e = 0; e < 8; e++) ones[e] = (bf16)1.0f;

#define STAGE_K(nb, j) do {                                                                \
    int X0_ = w * 1024 + l * 16;                                                           \
    const char* Kj_ = KbB + (size_t)(j) * 8192;                                            \
    gload16(Kj_ + swz(X0_),        (char*)lK[nb] + w * 1024);                              \
    gload16(Kj_ + swz(X0_ + 4096), (char*)lK[nb] + w * 1024 + 4096);                       \
} while (0)

    for (int half = 0; half < 2; half++) {
        int s = (half == 0) ? (15 - p) : p;          // heavy strip first
        int r0 = s * 128;
        int nblk = 2 * s + 2;
        int wrow = r0 + w * 32;
        const bf16* Qb = Q + ((size_t)bh * TT + wrow) * HD;
        // Q A-fragments: row=l&31, k=(l>>5)*8+e, per 16-d chunk kc
        bf16x8 qa[4];
#pragma unroll
        for (int kc = 0; kc < 4; kc++)
            qa[kc] = *(const bf16x8*)(Qb + (size_t)(l & 31) * HD + kc * 16 + (l >> 5) * 8);

        f32x16 oacc[2] = {};
        f32x16 lacc = {};

        STAGE_K(0, 0);
        __syncthreads();                             // lK[0] ready
        int cur = 0;
        for (int j = 0; j < nblk; j++) {
            if (j + 1 < nblk) STAGE_K(cur ^ 1, j + 1);   // async prefetch
            if (j * 64 <= wrow + 31) {               // wave-active guard (waves 0/1 skip last unit)
                // ---- QK^T: 2 kv-tiles x 4 k-chunks ----
                f32x16 sc[2];
#pragma unroll
                for (int r = 0; r < 16; r++) { sc[0][r] = -16.0f; sc[1][r] = -16.0f; }
                __builtin_amdgcn_s_setprio(1);
#pragma unroll
                for (int kc = 0; kc < 4; kc++)
#pragma unroll
                    for (int nj = 0; nj < 2; nj++) {
                        int rr = nj * 32 + (l & 31);
                        int L = rr * 128 + (kc * 16 + (l >> 5) * 8) * 2;
                        bf16x8 kb = *(const bf16x8*)((const char*)lK[cur] + (L ^ ((rr & 7) << 4)));
                        sc[nj] = MFMA32(qa[kc], kb, sc[nj]);
                    }
                __builtin_amdgcn_s_setprio(0);
                // ---- causal mask (diagonal-crossing units only) ----
                if (j * 64 + 63 > wrow) {
#pragma unroll
                    for (int nj = 0; nj < 2; nj++) {
                        int colg = j * 64 + nj * 32 + (l & 31);
#pragma unroll
                        for (int r = 0; r < 16; r++) {
                            int rowq = wrow + (r & 3) + 8 * (r >> 2) + 4 * (l >> 5);
                            if (colg > rowq) sc[nj][r] = -1e30f;
                        }
                    }
                }
                // ---- fixed-shift exp2, P -> lP (per-wave-private 32 rows) ----
                {
                    int prB = w * 32 + 4 * (l >> 5);
#pragma unroll
                    for (int nj = 0; nj < 2; nj++) {
                        int pc = nj * 32 + (l & 31);
#pragma unroll
                        for (int r = 0; r < 16; r++)
                            lP[(prB + (r & 3) + 8 * (r >> 2)) * 68 + pc] = (bf16)exp2f(sc[nj][r]);
                    }
                }
                // ---- V fragments direct from global (L2-hit); named regs, static idx ----
                bf16x8 vb[4][2];
#pragma unroll
                for (int kc = 0; kc < 4; kc++)
#pragma unroll
                    for (int dt = 0; dt < 2; dt++)
                        vb[kc][dt] = *(const bf16x8*)(Vb + (size_t)(dt * 32 + (l & 31)) * TT
                                                      + j * 64 + kc * 16 + (l >> 5) * 8);
                // ---- PV + denominator ----
                __builtin_amdgcn_s_setprio(1);
#pragma unroll
                for (int kc = 0; kc < 4; kc++) {
                    bf16x8 pa = *(const bf16x8*)&lP[(w * 32 + (l & 31)) * 68 + kc * 16 + (l >> 5) * 8];
                    lacc = MFMA32(pa, ones, lacc);
#pragma unroll
                    for (int dt = 0; dt < 2; dt++)
                        oacc[dt] = MFMA32(pa, vb[kc][dt], oacc[dt]);
                }
                __builtin_amdgcn_s_setprio(0);
            }
            __syncthreads();                         // drains STAGE; next buf ready
            cur ^= 1;
        }
        // ---- epilogue: O[tok][h*64+d] bf16 ----
#pragma unroll
        for (int r = 0; r < 16; r++) {
            int rq = (r & 3) + 8 * (r >> 2) + 4 * (l >> 5);
            int t = wrow + rq;
            float inv = 1.0f / lacc[r];
            size_t base = ((size_t)b * TT + t) * DM + h * HD;
#pragma unroll
            for (int dt = 0; dt < 2; dt++)
                O[base + dt * 32 + (l & 31)] = (bf16)(oacc[dt][r] * inv);
        }
    }
#undef STAGE_K
}

extern "C" void kernel_launch(void* const* d_in, const int* in_sizes, int n_in,
                              void* d_out, int out_size, void* d_ws, size_t ws_size,
                              hipStream_t stream) {
    const float* x    = (const float*)d_in[0];
    const float* Wqkv = (const float*)d_in[1];
    const float* Wout = (const float*)d_in[2];
    float* out = (float*)d_out;

    char* ws = (char*)d_ws;
    size_t off = 0;
    auto alloc = [&](size_t bytes) {
        void* p = ws + off;
        off += (bytes + 255) & ~(size_t)255;
        return p;
    };
    bf16* xb    = (bf16*)alloc((size_t)TOK * DM * 2);
    bf16* wqkvt = (bf16*)alloc((size_t)NQKV * DM * 2);
    bf16* woutt = (bf16*)alloc((size_t)DM * DM * 2);
    bf16* qr    = (bf16*)alloc((size_t)TOK * DM * 2);
    bf16* kr    = (bf16*)alloc((size_t)TOK * DM * 2);
    bf16* vt    = (bf16*)alloc((size_t)TOK * DM * 2);
    bf16* ob    = (bf16*)alloc((size_t)TOK * DM * 2);
    float* ct   = (float*)alloc((size_t)TT * 32 * 4);
    float* st   = (float*)alloc((size_t)TT * 32 * 4);
    (void)ws_size; (void)in_sizes; (void)n_in; (void)out_size;

    k_cvt<<<TOK * DM / 4 / 256, 256, 0, stream>>>(x, xb, TOK * DM);
    k_transpose_cvt<<<dim3(NQKV / 64, DM / 64), 256, 0, stream>>>(Wqkv, wqkvt, DM, NQKV);
    k_transpose_cvt<<<dim3(DM / 64, DM / 64), 256, 0, stream>>>(Wout, woutt, DM, DM);
    k_rope_tab<<<TT * 32 / 256, 256, 0, stream>>>(ct, st);
    // Q scale folds 1/sqrt(64) * log2(e) so softmax runs in exp2 domain (applied in GEMM epilogue)
    k_gemm_bt<1><<<dim3(NQKV / 128, TOK / 128), 256, 0, stream>>>(
        xb, wqkvt, TOK, NQKV, DM, nullptr, qr, kr, vt,
        ct, st, 0.125f * 1.4426950408889634f);
    k_attn<<<dim3(16, BB * NH), 256, 0, stream>>>(qr, kr, vt, ob);
    k_gemm_bt<2><<<dim3(DM / 128, TOK / 128), 256, 0, stream>>>(
        ob, woutt, TOK, DM, DM, out, nullptr, nullptr, nullptr,
        nullptr, nullptr, 0.0f);
}

// Round 11
// 205.982 us; speedup vs baseline: 1.7931x; 1.7931x over previous
//
#include <hip/hip_runtime.h>
#include <cstdint>
#include <cstddef>

typedef __bf16 bf16;
typedef __bf16 bf16x8 __attribute__((ext_vector_type(8)));
typedef __bf16 bf16x4 __attribute__((ext_vector_type(4)));
typedef float  f32x4  __attribute__((ext_vector_type(4)));
typedef float  f32x16 __attribute__((ext_vector_type(16)));

#define MFMA16(a, b, c) __builtin_amdgcn_mfma_f32_16x16x32_bf16((a), (b), (c), 0, 0, 0)
#define MFMA32(a, b, c) __builtin_amdgcn_mfma_f32_32x32x16_bf16((a), (b), (c), 0, 0, 0)

static constexpr int BB   = 4;
static constexpr int TT   = 2048;
static constexpr int DM   = 1024;
static constexpr int NH   = 16;
static constexpr int HD   = 64;
static constexpr int TOK  = BB * TT;    // 8192
static constexpr int NQKV = 3 * DM;     // 3072

// async global->LDS, 16B per lane; dst must be wave-uniform base (HW adds lane*16)
__device__ inline void gload16(const void* g, void* l) {
    __builtin_amdgcn_global_load_lds((const __attribute__((address_space(1))) void*)g,
                                     (__attribute__((address_space(3))) void*)l, 16, 0, 0);
}

// XOR-swizzle for [64][128B] row-major LDS tiles: spread each column across 8 slots
__device__ inline int swz(int x) { return x ^ ((x >> 3) & 0x70); }

// ---------------- elementwise f32 -> bf16 ----------------
__global__ void k_cvt(const float* __restrict__ in, bf16* __restrict__ out, int n) {
    int i = (blockIdx.x * blockDim.x + threadIdx.x) * 4;
    if (i >= n) return;
    float4 v = *(const float4*)(in + i);
    bf16x4 o;
    o[0] = (bf16)v.x; o[1] = (bf16)v.y; o[2] = (bf16)v.z; o[3] = (bf16)v.w;
    *(bf16x4*)(out + i) = o;
}

// ---------------- transpose + convert: in f32 [R][C] -> out bf16 [C][R] ----------------
__global__ void k_transpose_cvt(const float* __restrict__ in, bf16* __restrict__ out,
                                int R, int C) {
    __shared__ bf16 tl[64 * 72];
    int tid = threadIdx.x;
    int c0 = blockIdx.x * 64, r0 = blockIdx.y * 64;
#pragma unroll
    for (int rep = 0; rep < 4; rep++) {
        int r = rep * 16 + (tid >> 4);
        int c = (tid & 15) * 4;
        float4 v = *(const float4*)(in + (size_t)(r0 + r) * C + c0 + c);
        tl[r * 72 + c + 0] = (bf16)v.x;
        tl[r * 72 + c + 1] = (bf16)v.y;
        tl[r * 72 + c + 2] = (bf16)v.z;
        tl[r * 72 + c + 3] = (bf16)v.w;
    }
    __syncthreads();
#pragma unroll
    for (int rep = 0; rep < 4; rep++) {
        int cc = rep * 16 + (tid >> 4);
        int rr = (tid & 15) * 4;
        bf16x4 o;
        o[0] = tl[(rr + 0) * 72 + cc];
        o[1] = tl[(rr + 1) * 72 + cc];
        o[2] = tl[(rr + 2) * 72 + cc];
        o[3] = tl[(rr + 3) * 72 + cc];
        *(bf16x4*)(out + (size_t)(c0 + cc) * R + r0 + rr) = o;
    }
}

// ---------------- RoPE cos/sin table ----------------
__global__ void k_rope_tab(float* __restrict__ ct, float* __restrict__ st) {
    int i = blockIdx.x * blockDim.x + threadIdx.x;   // TT*32
    int t = i >> 5, j = i & 31;
    float invf = powf(10000.0f, -(float)j * (1.0f / 32.0f));
    float a = (float)t * invf;
    ct[i] = cosf(a);
    st[i] = sinf(a);
}

// ---------------- GEMM: C[M][N] = A[M][K] @ Bt[N][K]^T, bf16 in, f32 acc ----------------
// m97 structure: global_load_lds width=16, linear [128][64] LDS, 2 barriers/K-step.
// MODE 1: fused-RoPE scatter epilogue -> qbuf/kbuf [B,H,T,64] (roped, Q pre-scaled),
//         vbuf [B,H,64,T] (QKV projection). Each wave's 64 n-cols = one head.
// MODE 2: f32 row-major out (final projection)
template <int MODE>
__global__ __launch_bounds__(256) void k_gemm_bt(
    const bf16* __restrict__ A, const bf16* __restrict__ Bt,
    int M, int N, int K,
    float* __restrict__ outF,
    bf16* __restrict__ qbuf, bf16* __restrict__ kbuf, bf16* __restrict__ vbuf,
    const float* __restrict__ ct, const float* __restrict__ st, float qscale) {
    __shared__ bf16 lA[128 * 64];
    __shared__ bf16 lB[128 * 64];
    int tid = threadIdx.x;
    int l = tid & 63, wid = tid >> 6;
    int wm = wid >> 1, wn = wid & 1;                 // 2x2 waves of 64x64
    int bn = blockIdx.x, bm = blockIdx.y;
    const bf16* Ab = A + (size_t)bm * 128 * K;
    const bf16* Bb = Bt + (size_t)bn * 128 * K;
    int srow = l >> 3, scol = (l & 7) * 8;           // within an 8-row chunk
    f32x4 acc[4][4] = {};
    for (int kt = 0; kt < K; kt += 64) {
        __syncthreads();                             // previous iter's ds_reads done
#pragma unroll
        for (int i = 0; i < 4; i++) {
            int chunk = wid * 4 + i;                 // 16 chunks x 512 elems (8 rows)
            gload16(Ab + (size_t)(chunk * 8 + srow) * K + kt + scol, &lA[chunk * 512]);
            gload16(Bb + (size_t)(chunk * 8 + srow) * K + kt + scol, &lB[chunk * 512]);
        }
        __syncthreads();                             // drains vmcnt (compiler-emitted)
#pragma unroll
        for (int kk = 0; kk < 2; kk++) {
            bf16x8 af[4], bfr[4];
#pragma unroll
            for (int mi = 0; mi < 4; mi++)
                af[mi] = *(const bf16x8*)&lA[(wm * 64 + mi * 16 + (l & 15)) * 64 + kk * 32 + (l >> 4) * 8];
#pragma unroll
            for (int ni = 0; ni < 4; ni++)
                bfr[ni] = *(const bf16x8*)&lB[(wn * 64 + ni * 16 + (l & 15)) * 64 + kk * 32 + (l >> 4) * 8];
#pragma unroll
            for (int mi = 0; mi < 4; mi++)
#pragma unroll
                for (int ni = 0; ni < 4; ni++)
                    acc[mi][ni] = MFMA16(af[mi], bfr[ni], acc[mi][ni]);
        }
    }
    if (MODE == 2) {
#pragma unroll
        for (int mi = 0; mi < 4; mi++) {
            int m0 = bm * 128 + wm * 64 + mi * 16 + ((l >> 4) << 2);
#pragma unroll
            for (int ni = 0; ni < 4; ni++) {
                int n = bn * 128 + wn * 64 + ni * 16 + (l & 15);
#pragma unroll
                for (int rj = 0; rj < 4; rj++)
                    outF[(size_t)(m0 + rj) * N + n] = acc[mi][ni][rj];
            }
        }
    } else {
        int n0 = bn * 128 + wn * 64;                 // wave-uniform; 64-col span = one head
        int sQ = n0 >> 10;
        int h = (n0 & 1023) >> 6;
        if (sQ == 2) {                               // V: pre-transposed [B,H,64,T]
#pragma unroll
            for (int ni = 0; ni < 4; ni++) {
                int d = ni * 16 + (l & 15);
#pragma unroll
                for (int mi = 0; mi < 4; mi++) {
                    int m0 = bm * 128 + wm * 64 + mi * 16 + ((l >> 4) << 2);
                    int b = m0 >> 11, t0 = m0 & 2047;
                    bf16x4 pv;
#pragma unroll
                    for (int rj = 0; rj < 4; rj++) pv[rj] = (bf16)acc[mi][ni][rj];
                    *(bf16x4*)(vbuf + ((size_t)((b * NH + h) * HD + d)) * TT + t0) = pv;
                }
            }
        } else {                                     // Q/K: RoPE in f32, then scatter
            float qs = (sQ == 0) ? qscale : 1.0f;
            bf16* obuf = (sQ == 0) ? qbuf : kbuf;
#pragma unroll
            for (int mi = 0; mi < 4; mi++) {
                int m0 = bm * 128 + wm * 64 + mi * 16 + ((l >> 4) << 2);
                int b = m0 >> 11, t0 = m0 & 2047;
#pragma unroll
                for (int rj = 0; rj < 4; rj++) {
                    int t = t0 + rj;
                    bf16* dst = obuf + ((size_t)(b * NH + h) * TT + t) * HD;
                    const float* crow = ct + t * 32;
                    const float* srow = st + t * 32;
#pragma unroll
                    for (int ni2 = 0; ni2 < 2; ni2++) {
                        int d = ni2 * 16 + (l & 15);
                        float cs = crow[d], sn = srow[d];
                        float a  = acc[mi][ni2][rj];
                        float b2 = acc[mi][ni2 + 2][rj];
                        dst[d]      = (bf16)(qs * (a  * cs - b2 * sn));
                        dst[d + 32] = (bf16)(qs * (b2 * cs + a  * sn));
                    }
                }
            }
        }
    }
}

// ---------------- flash attention, 32x32 MFMA retile (round-6 skeleton) ----------------
// Q,K [B*H,T,64] (Q pre-scaled by log2e/sqrt(hd), both roped), Vt [B*H,64,T].
// Block (4 waves) owns a PAIR of 128-row q-strips (15-p, p): 36 kv-units/block,
// all 512 blocks equal. Wave w computes q-rows [w*32, w*32+32) via 32x32x16 MFMAs.
//   A-frag: row=l&31, k=(l>>5)*8+e.  C layout: col=l&31, row=(r&3)+8*(r>>2)+4*(l>>5).
// K/V tiles staged in LDS (dbuf, DMA, pre-swizzled source); lP [128 q][64 kv] bf16
// = 16KB (round-10 bug: was declared 8KB -> OOB garbage -> NaN), stride 128B,
// XOR (row&7)<<4 swizzle.
// Fixed-shift softmax: acc init -16, exp2, no max/shuffles; denom via ones-MFMA.
// launch_bounds(256,2): VGPR cap 256 (round-9's (256,4) forced 64 VGPR -> spill).
// XCD remap keeps each bh's K/V L2-resident (FETCH 192->26MB, round 7).
__global__ __launch_bounds__(256, 2) void k_attn(
    const bf16* __restrict__ Q, const bf16* __restrict__ K,
    const bf16* __restrict__ Vt, bf16* __restrict__ O) {
    __shared__ bf16 lK[2][4096];    // [64 kv][64 d] swizzled, 8KB each
    __shared__ bf16 lV[2][4096];    // [64 d][64 t] swizzled
    __shared__ bf16 lP[8192];       // [128 q][64 kv], stride 128B, XOR swizzled (16KB)
    int tid = threadIdx.x;
    int l = tid & 63, w = tid >> 6;
    // XCD-aware remap: grid (8,64); xcd = blockIdx.x; 8 bh per XCD
    int bx = blockIdx.x, by = blockIdx.y;
    int bh = bx * 8 + (by >> 3);
    int p = by & 7;                 // pair index 0..7
    const char* KbB = (const char*)(K + (size_t)bh * TT * HD);
    const char* VbB = (const char*)(Vt + (size_t)bh * HD * TT);
    int b = bh >> 4, h = bh & 15;

    bf16x8 ones;
#pragma unroll
    for (int e = 0; e < 8; e++) ones[e] = (bf16)1.0f;

#define STAGE_KV(nb, j) do {                                                               \
    int X0_ = w * 1024 + l * 16;                                                           \
    const char* Kj_ = KbB + (size_t)(j) * 8192;                                            \
    gload16(Kj_ + swz(X0_),        (char*)lK[nb] + w * 1024);                              \
    gload16(Kj_ + swz(X0_ + 4096), (char*)lK[nb] + w * 1024 + 4096);                       \
    int o0_ = swz(X0_), o1_ = swz(X0_ + 4096);                                             \
    gload16(VbB + (size_t)(o0_ >> 7) * (TT * 2) + (size_t)(j) * 128 + (o0_ & 127),         \
            (char*)lV[nb] + w * 1024);                                                     \
    gload16(VbB + (size_t)(o1_ >> 7) * (TT * 2) + (size_t)(j) * 128 + (o1_ & 127),         \
            (char*)lV[nb] + w * 1024 + 4096);                                              \
} while (0)

    for (int half = 0; half < 2; half++) {
        int s = (half == 0) ? (15 - p) : p;          // heavy strip first
        int r0 = s * 128;
        int nblk = 2 * s + 2;
        int wrow = r0 + w * 32;
        const bf16* Qb = Q + ((size_t)bh * TT + wrow) * HD;
        // Q A-fragments: row=l&31, k-chunk kc, elems (l>>5)*8..+8
        bf16x8 qa[4];
#pragma unroll
        for (int kc = 0; kc < 4; kc++)
            qa[kc] = *(const bf16x8*)(Qb + (size_t)(l & 31) * HD + kc * 16 + (l >> 5) * 8);

        f32x16 oacc[2] = {};
        f32x16 lacc = {};

        STAGE_KV(0, 0);
        __syncthreads();                             // lK[0]/lV[0] ready
        int cur = 0;
        for (int j = 0; j < nblk; j++) {
            if (j + 1 < nblk) STAGE_KV(cur ^ 1, j + 1);  // async prefetch under compute
            if (j * 64 <= wrow + 31) {               // wave-active guard (barrier stays outside)
                // ---- QK^T: 2 kv-subtiles x 4 k-chunks, acc pre-shifted by -16 ----
                f32x16 sc[2];
#pragma unroll
                for (int r = 0; r < 16; r++) { sc[0][r] = -16.0f; sc[1][r] = -16.0f; }
                __builtin_amdgcn_s_setprio(1);
#pragma unroll
                for (int kc = 0; kc < 4; kc++)
#pragma unroll
                    for (int nj = 0; nj < 2; nj++) {
                        int rr = nj * 32 + (l & 31);
                        int L = rr * 128 + ((kc * 16 + (l >> 5) * 8) * 2 ^ ((rr & 7) << 4));
                        bf16x8 kb = *(const bf16x8*)((const char*)lK[cur] + L);
                        sc[nj] = MFMA32(qa[kc], kb, sc[nj]);
                    }
                __builtin_amdgcn_s_setprio(0);
                // ---- causal mask (diagonal-crossing units only) ----
                if (j * 64 + 63 > wrow) {
#pragma unroll
                    for (int nj = 0; nj < 2; nj++) {
                        int colg = j * 64 + nj * 32 + (l & 31);
#pragma unroll
                        for (int r = 0; r < 16; r++) {
                            int rowq = wrow + (r & 3) + 8 * (r >> 2) + 4 * (l >> 5);
                            if (colg > rowq) sc[nj][r] = -1e30f;
                        }
                    }
                }
                // ---- fixed-shift exp2, P -> lP (per-wave-private 32 rows, swizzled) ----
                {
                    int prB = w * 32 + 4 * (l >> 5);
#pragma unroll
                    for (int nj = 0; nj < 2; nj++) {
                        int pcB = (nj * 32 + (l & 31)) * 2;
#pragma unroll
                        for (int r = 0; r < 16; r++) {
                            int row = prB + (r & 3) + 8 * (r >> 2);
                            *(bf16*)((char*)lP + row * 128 + (pcB ^ ((row & 7) << 4)))
                                = (bf16)exp2f(sc[nj][r]);
                        }
                    }
                }
                // ---- PV + denominator: P A-frag row=l&31, V B-frag col=l&31=d ----
                __builtin_amdgcn_s_setprio(1);
#pragma unroll
                for (int kc = 0; kc < 4; kc++) {
                    int pr = w * 32 + (l & 31);
                    bf16x8 pa = *(const bf16x8*)((const char*)lP + pr * 128
                                 + ((kc * 32 + (l >> 5) * 16) ^ ((pr & 7) << 4)));
                    lacc = MFMA32(pa, ones, lacc);
#pragma unroll
                    for (int dt = 0; dt < 2; dt++) {
                        int dd = dt * 32 + (l & 31);
                        int L = dd * 128 + ((kc * 16 + (l >> 5) * 8) * 2 ^ ((dd & 7) << 4));
                        bf16x8 vbf = *(const bf16x8*)((const char*)lV[cur] + L);
                        oacc[dt] = MFMA32(pa, vbf, oacc[dt]);
                    }
                }
                __builtin_amdgcn_s_setprio(0);
            }
            __syncthreads();                         // drains STAGE; next buf ready
            cur ^= 1;
        }
        // ---- epilogue: O[tok][h*64+d] bf16 ----
#pragma unroll
        for (int r = 0; r < 16; r++) {
            int rq = (r & 3) + 8 * (r >> 2) + 4 * (l >> 5);
            int t = wrow + rq;
            float inv = 1.0f / lacc[r];
            size_t base = ((size_t)b * TT + t) * DM + h * HD;
#pragma unroll
            for (int dt = 0; dt < 2; dt++)
                O[base + dt * 32 + (l & 31)] = (bf16)(oacc[dt][r] * inv);
        }
    }
#undef STAGE_KV
}

extern "C" void kernel_launch(void* const* d_in, const int* in_sizes, int n_in,
                              void* d_out, int out_size, void* d_ws, size_t ws_size,
                              hipStream_t stream) {
    const float* x    = (const float*)d_in[0];
    const float* Wqkv = (const float*)d_in[1];
    const float* Wout = (const float*)d_in[2];
    float* out = (float*)d_out;

    char* ws = (char*)d_ws;
    size_t off = 0;
    auto alloc = [&](size_t bytes) {
        void* p = ws + off;
        off += (bytes + 255) & ~(size_t)255;
        return p;
    };
    bf16* xb    = (bf16*)alloc((size_t)TOK * DM * 2);
    bf16* wqkvt = (bf16*)alloc((size_t)NQKV * DM * 2);
    bf16* woutt = (bf16*)alloc((size_t)DM * DM * 2);
    bf16* qr    = (bf16*)alloc((size_t)TOK * DM * 2);
    bf16* kr    = (bf16*)alloc((size_t)TOK * DM * 2);
    bf16* vt    = (bf16*)alloc((size_t)TOK * DM * 2);
    bf16* ob    = (bf16*)alloc((size_t)TOK * DM * 2);
    float* ct   = (float*)alloc((size_t)TT * 32 * 4);
    float* st   = (float*)alloc((size_t)TT * 32 * 4);
    (void)ws_size; (void)in_sizes; (void)n_in; (void)out_size;

    k_cvt<<<TOK * DM / 4 / 256, 256, 0, stream>>>(x, xb, TOK * DM);
    k_transpose_cvt<<<dim3(NQKV / 64, DM / 64), 256, 0, stream>>>(Wqkv, wqkvt, DM, NQKV);
    k_transpose_cvt<<<dim3(DM / 64, DM / 64), 256, 0, stream>>>(Wout, woutt, DM, DM);
    k_rope_tab<<<TT * 32 / 256, 256, 0, stream>>>(ct, st);
    // Q scale folds 1/sqrt(64) * log2(e) so softmax runs in exp2 domain (applied in GEMM epilogue)
    k_gemm_bt<1><<<dim3(NQKV / 128, TOK / 128), 256, 0, stream>>>(
        xb, wqkvt, TOK, NQKV, DM, nullptr, qr, kr, vt,
        ct, st, 0.125f * 1.4426950408889634f);
    k_attn<<<dim3(8, BB * NH), 256, 0, stream>>>(qr, kr, vt, ob);
    k_gemm_bt<2><<<dim3(DM / 128, TOK / 128), 256, 0, stream>>>(
        ob, woutt, TOK, DM, DM, out, nullptr, nullptr, nullptr,
        nullptr, nullptr, 0.0f);
}

// Round 12
// 188.963 us; speedup vs baseline: 1.9546x; 1.0901x over previous
//
#include <hip/hip_runtime.h>
#include <cstdint>
#include <cstddef>

typedef __bf16 bf16;
typedef __bf16 bf16x8 __attribute__((ext_vector_type(8)));
typedef __bf16 bf16x4 __attribute__((ext_vector_type(4)));
typedef float  f32x4  __attribute__((ext_vector_type(4)));
typedef float  f32x16 __attribute__((ext_vector_type(16)));

#define MFMA16(a, b, c) __builtin_amdgcn_mfma_f32_16x16x32_bf16((a), (b), (c), 0, 0, 0)
#define MFMA32(a, b, c) __builtin_amdgcn_mfma_f32_32x32x16_bf16((a), (b), (c), 0, 0, 0)

static constexpr int BB   = 4;
static constexpr int TT   = 2048;
static constexpr int DM   = 1024;
static constexpr int NH   = 16;
static constexpr int HD   = 64;
static constexpr int TOK  = BB * TT;    // 8192
static constexpr int NQKV = 3 * DM;     // 3072

// async global->LDS, 16B per lane; dst must be wave-uniform base (HW adds lane*16)
__device__ inline void gload16(const void* g, void* l) {
    __builtin_amdgcn_global_load_lds((const __attribute__((address_space(1))) void*)g,
                                     (__attribute__((address_space(3))) void*)l, 16, 0, 0);
}

// XOR-swizzle for [R][128B] row-major LDS tiles: spread each 16B column slot
// across 8 slots by row&7 (involution; preserves row bits >=7)
__device__ inline int swz(int x) { return x ^ ((x >> 3) & 0x70); }

// ---------------- elementwise f32 -> bf16 ----------------
__global__ void k_cvt(const float* __restrict__ in, bf16* __restrict__ out, int n) {
    int i = (blockIdx.x * blockDim.x + threadIdx.x) * 4;
    if (i >= n) return;
    float4 v = *(const float4*)(in + i);
    bf16x4 o;
    o[0] = (bf16)v.x; o[1] = (bf16)v.y; o[2] = (bf16)v.z; o[3] = (bf16)v.w;
    *(bf16x4*)(out + i) = o;
}

// ---------------- transpose + convert: in f32 [R][C] -> out bf16 [C][R] ----------------
__global__ void k_transpose_cvt(const float* __restrict__ in, bf16* __restrict__ out,
                                int R, int C) {
    __shared__ bf16 tl[64 * 72];
    int tid = threadIdx.x;
    int c0 = blockIdx.x * 64, r0 = blockIdx.y * 64;
#pragma unroll
    for (int rep = 0; rep < 4; rep++) {
        int r = rep * 16 + (tid >> 4);
        int c = (tid & 15) * 4;
        float4 v = *(const float4*)(in + (size_t)(r0 + r) * C + c0 + c);
        tl[r * 72 + c + 0] = (bf16)v.x;
        tl[r * 72 + c + 1] = (bf16)v.y;
        tl[r * 72 + c + 2] = (bf16)v.z;
        tl[r * 72 + c + 3] = (bf16)v.w;
    }
    __syncthreads();
#pragma unroll
    for (int rep = 0; rep < 4; rep++) {
        int cc = rep * 16 + (tid >> 4);
        int rr = (tid & 15) * 4;
        bf16x4 o;
        o[0] = tl[(rr + 0) * 72 + cc];
        o[1] = tl[(rr + 1) * 72 + cc];
        o[2] = tl[(rr + 2) * 72 + cc];
        o[3] = tl[(rr + 3) * 72 + cc];
        *(bf16x4*)(out + (size_t)(c0 + cc) * R + r0 + rr) = o;
    }
}

// ---------------- RoPE cos/sin table ----------------
__global__ void k_rope_tab(float* __restrict__ ct, float* __restrict__ st) {
    int i = blockIdx.x * blockDim.x + threadIdx.x;   // TT*32
    int t = i >> 5, j = i & 31;
    float invf = powf(10000.0f, -(float)j * (1.0f / 32.0f));
    float a = (float)t * invf;
    ct[i] = cosf(a);
    st[i] = sinf(a);
}

// ---------------- GEMM: C[M][N] = A[M][K] @ Bt[N][K]^T, bf16 in, f32 acc ----------------
// Round-12: (1) T2 conflict fix — pre-swizzled gload source + swz() ds_reads
// (16-way row-column conflict -> 2-way free; was 18.9M conflict cycles/dispatch);
// (2) double-buffered LDS, STAGE(next) before compute(cur), ONE barrier/K-step
// (T3 minimum recipe; stage latency hides under MFMA).
// MODE 1: fused-RoPE scatter epilogue -> qbuf/kbuf [B,H,T,64] (roped, Q pre-scaled),
//         vbuf [B,H,64,T]. Each wave's 64 n-cols = one head.
// MODE 2: f32 row-major out (final projection)
template <int MODE>
__global__ __launch_bounds__(256) void k_gemm_bt(
    const bf16* __restrict__ A, const bf16* __restrict__ Bt,
    int M, int N, int K,
    float* __restrict__ outF,
    bf16* __restrict__ qbuf, bf16* __restrict__ kbuf, bf16* __restrict__ vbuf,
    const float* __restrict__ ct, const float* __restrict__ st, float qscale) {
    __shared__ bf16 lA[2][128 * 64];   // [128 rows][128B], swizzled content
    __shared__ bf16 lB[2][128 * 64];
    int tid = threadIdx.x;
    int l = tid & 63, wid = tid >> 6;
    int wm = wid >> 1, wn = wid & 1;                 // 2x2 waves of 64x64
    int bn = blockIdx.x, bm = blockIdx.y;
    const char* AbB = (const char*)(A + (size_t)bm * 128 * K);
    const char* BbB = (const char*)(Bt + (size_t)bn * 128 * K);
    const size_t KB = (size_t)K * 2;                 // global row stride in bytes
    f32x4 acc[4][4] = {};

    // stage one 64-col K-slice into buf nb: LDS linear dest, swizzled global source
#define GSTAGE(nb, kt) do {                                                                \
    _Pragma("unroll") for (int i = 0; i < 4; i++) {                                        \
        int cb = (wid * 4 + i) * 1024;               /* wave-uniform chunk base (8 rows) */\
        int Xs = swz(cb + l * 16);                   /* per-lane swizzled linear offset  */\
        gload16(AbB + (size_t)(Xs >> 7) * KB + (size_t)(kt) * 2 + (Xs & 127),              \
                (char*)lA[nb] + cb);                                                       \
        gload16(BbB + (size_t)(Xs >> 7) * KB + (size_t)(kt) * 2 + (Xs & 127),              \
                (char*)lB[nb] + cb);                                                       \
    }                                                                                      \
} while (0)

    GSTAGE(0, 0);
    __syncthreads();                                 // prologue drain
    int cur = 0;
    int nsteps = K >> 6;
    for (int t = 0; t < nsteps; t++) {
        if (t + 1 < nsteps) GSTAGE(cur ^ 1, (t + 1) << 6);   // prefetch under compute
#pragma unroll
        for (int kk = 0; kk < 2; kk++) {
            bf16x8 af[4], bfr[4];
#pragma unroll
            for (int mi = 0; mi < 4; mi++) {
                int rr = wm * 64 + mi * 16 + (l & 15);
                int L = rr * 128 + (kk * 32 + (l >> 4) * 8) * 2;
                af[mi] = *(const bf16x8*)((const char*)lA[cur] + swz(L));
            }
#pragma unroll
            for (int ni = 0; ni < 4; ni++) {
                int rr = wn * 64 + ni * 16 + (l & 15);
                int L = rr * 128 + (kk * 32 + (l >> 4) * 8) * 2;
                bfr[ni] = *(const bf16x8*)((const char*)lB[cur] + swz(L));
            }
#pragma unroll
            for (int mi = 0; mi < 4; mi++)
#pragma unroll
                for (int ni = 0; ni < 4; ni++)
                    acc[mi][ni] = MFMA16(af[mi], bfr[ni], acc[mi][ni]);
        }
        __syncthreads();                             // reads(cur) done + stage(cur^1) drained
        cur ^= 1;
    }
#undef GSTAGE

    if (MODE == 2) {
#pragma unroll
        for (int mi = 0; mi < 4; mi++) {
            int m0 = bm * 128 + wm * 64 + mi * 16 + ((l >> 4) << 2);
#pragma unroll
            for (int ni = 0; ni < 4; ni++) {
                int n = bn * 128 + wn * 64 + ni * 16 + (l & 15);
#pragma unroll
                for (int rj = 0; rj < 4; rj++)
                    outF[(size_t)(m0 + rj) * N + n] = acc[mi][ni][rj];
            }
        }
    } else {
        int n0 = bn * 128 + wn * 64;                 // wave-uniform; 64-col span = one head
        int sQ = n0 >> 10;
        int h = (n0 & 1023) >> 6;
        if (sQ == 2) {                               // V: pre-transposed [B,H,64,T]
#pragma unroll
            for (int ni = 0; ni < 4; ni++) {
                int d = ni * 16 + (l & 15);
#pragma unroll
                for (int mi = 0; mi < 4; mi++) {
                    int m0 = bm * 128 + wm * 64 + mi * 16 + ((l >> 4) << 2);
                    int b = m0 >> 11, t0 = m0 & 2047;
                    bf16x4 pv;
#pragma unroll
                    for (int rj = 0; rj < 4; rj++) pv[rj] = (bf16)acc[mi][ni][rj];
                    *(bf16x4*)(vbuf + ((size_t)((b * NH + h) * HD + d)) * TT + t0) = pv;
                }
            }
        } else {                                     // Q/K: RoPE in f32, then scatter
            float qs = (sQ == 0) ? qscale : 1.0f;
            bf16* obuf = (sQ == 0) ? qbuf : kbuf;
#pragma unroll
            for (int mi = 0; mi < 4; mi++) {
                int m0 = bm * 128 + wm * 64 + mi * 16 + ((l >> 4) << 2);
                int b = m0 >> 11, t0 = m0 & 2047;
#pragma unroll
                for (int rj = 0; rj < 4; rj++) {
                    int t = t0 + rj;
                    bf16* dst = obuf + ((size_t)(b * NH + h) * TT + t) * HD;
                    const float* crow = ct + t * 32;
                    const float* srow = st + t * 32;
#pragma unroll
                    for (int ni2 = 0; ni2 < 2; ni2++) {
                        int d = ni2 * 16 + (l & 15);
                        float cs = crow[d], sn = srow[d];
                        float a  = acc[mi][ni2][rj];
                        float b2 = acc[mi][ni2 + 2][rj];
                        dst[d]      = (bf16)(qs * (a  * cs - b2 * sn));
                        dst[d + 32] = (bf16)(qs * (b2 * cs + a  * sn));
                    }
                }
            }
        }
    }
}

// ---------------- flash attention, 32x32 MFMA retile (round-11, unchanged) ----------------
// Q,K [B*H,T,64] (Q pre-scaled by log2e/sqrt(hd), both roped), Vt [B*H,64,T].
// Block (4 waves) owns a PAIR of 128-row q-strips (15-p, p): 36 kv-units/block,
// all 512 blocks equal. Wave w computes q-rows [w*32, w*32+32) via 32x32x16 MFMAs.
//   A-frag: row=l&31, k=(l>>5)*8+e.  C layout: col=l&31, row=(r&3)+8*(r>>2)+4*(l>>5).
// K/V tiles staged in LDS (dbuf, DMA, pre-swizzled source); lP [128 q][64 kv] bf16
// stride 128B, XOR (row&7)<<4 swizzle. Fixed-shift softmax (acc init -16, exp2);
// denominator via ones-MFMA. XCD remap keeps each bh's K/V L2-resident.
__global__ __launch_bounds__(256, 2) void k_attn(
    const bf16* __restrict__ Q, const bf16* __restrict__ K,
    const bf16* __restrict__ Vt, bf16* __restrict__ O) {
    __shared__ bf16 lK[2][4096];    // [64 kv][64 d] swizzled, 8KB each
    __shared__ bf16 lV[2][4096];    // [64 d][64 t] swizzled
    __shared__ bf16 lP[8192];       // [128 q][64 kv], stride 128B, XOR swizzled (16KB)
    int tid = threadIdx.x;
    int l = tid & 63, w = tid >> 6;
    // XCD-aware remap: grid (8,64); xcd = blockIdx.x; 8 bh per XCD
    int bx = blockIdx.x, by = blockIdx.y;
    int bh = bx * 8 + (by >> 3);
    int p = by & 7;                 // pair index 0..7
    const char* KbB = (const char*)(K + (size_t)bh * TT * HD);
    const char* VbB = (const char*)(Vt + (size_t)bh * HD * TT);
    int b = bh >> 4, h = bh & 15;

    bf16x8 ones;
#pragma unroll
    for (int e = 0; e < 8; e++) ones[e] = (bf16)1.0f;

#define STAGE_KV(nb, j) do {                                                               \
    int X0_ = w * 1024 + l * 16;                                                           \
    const char* Kj_ = KbB + (size_t)(j) * 8192;                                            \
    gload16(Kj_ + swz(X0_),        (char*)lK[nb] + w * 1024);                              \
    gload16(Kj_ + swz(X0_ + 4096), (char*)lK[nb] + w * 1024 + 4096);                       \
    int o0_ = swz(X0_), o1_ = swz(X0_ + 4096);                                             \
    gload16(VbB + (size_t)(o0_ >> 7) * (TT * 2) + (size_t)(j) * 128 + (o0_ & 127),         \
            (char*)lV[nb] + w * 1024);                                                     \
    gload16(VbB + (size_t)(o1_ >> 7) * (TT * 2) + (size_t)(j) * 128 + (o1_ & 127),         \
            (char*)lV[nb] + w * 1024 + 4096);                                              \
} while (0)

    for (int half = 0; half < 2; half++) {
        int s = (half == 0) ? (15 - p) : p;          // heavy strip first
        int r0 = s * 128;
        int nblk = 2 * s + 2;
        int wrow = r0 + w * 32;
        const bf16* Qb = Q + ((size_t)bh * TT + wrow) * HD;
        // Q A-fragments: row=l&31, k-chunk kc, elems (l>>5)*8..+8
        bf16x8 qa[4];
#pragma unroll
        for (int kc = 0; kc < 4; kc++)
            qa[kc] = *(const bf16x8*)(Qb + (size_t)(l & 31) * HD + kc * 16 + (l >> 5) * 8);

        f32x16 oacc[2] = {};
        f32x16 lacc = {};

        STAGE_KV(0, 0);
        __syncthreads();                             // lK[0]/lV[0] ready
        int cur = 0;
        for (int j = 0; j < nblk; j++) {
            if (j + 1 < nblk) STAGE_KV(cur ^ 1, j + 1);  // async prefetch under compute
            if (j * 64 <= wrow + 31) {               // wave-active guard (barrier stays outside)
                // ---- QK^T: 2 kv-subtiles x 4 k-chunks, acc pre-shifted by -16 ----
                f32x16 sc[2];
#pragma unroll
                for (int r = 0; r < 16; r++) { sc[0][r] = -16.0f; sc[1][r] = -16.0f; }
                __builtin_amdgcn_s_setprio(1);
#pragma unroll
                for (int kc = 0; kc < 4; kc++)
#pragma unroll
                    for (int nj = 0; nj < 2; nj++) {
                        int rr = nj * 32 + (l & 31);
                        int L = rr * 128 + ((kc * 16 + (l >> 5) * 8) * 2 ^ ((rr & 7) << 4));
                        bf16x8 kb = *(const bf16x8*)((const char*)lK[cur] + L);
                        sc[nj] = MFMA32(qa[kc], kb, sc[nj]);
                    }
                __builtin_amdgcn_s_setprio(0);
                // ---- causal mask (diagonal-crossing units only) ----
                if (j * 64 + 63 > wrow) {
#pragma unroll
                    for (int nj = 0; nj < 2; nj++) {
                        int colg = j * 64 + nj * 32 + (l & 31);
#pragma unroll
                        for (int r = 0; r < 16; r++) {
                            int rowq = wrow + (r & 3) + 8 * (r >> 2) + 4 * (l >> 5);
                            if (colg > rowq) sc[nj][r] = -1e30f;
                        }
                    }
                }
                // ---- fixed-shift exp2, P -> lP (per-wave-private 32 rows, swizzled) ----
                {
                    int prB = w * 32 + 4 * (l >> 5);
#pragma unroll
                    for (int nj = 0; nj < 2; nj++) {
                        int pcB = (nj * 32 + (l & 31)) * 2;
#pragma unroll
                        for (int r = 0; r < 16; r++) {
                            int row = prB + (r & 3) + 8 * (r >> 2);
                            *(bf16*)((char*)lP + row * 128 + (pcB ^ ((row & 7) << 4)))
                                = (bf16)exp2f(sc[nj][r]);
                        }
                    }
                }
                // ---- PV + denominator: P A-frag row=l&31, V B-frag col=l&31=d ----
                __builtin_amdgcn_s_setprio(1);
#pragma unroll
                for (int kc = 0; kc < 4; kc++) {
                    int pr = w * 32 + (l & 31);
                    bf16x8 pa = *(const bf16x8*)((const char*)lP + pr * 128
                                 + ((kc * 32 + (l >> 5) * 16) ^ ((pr & 7) << 4)));
                    lacc = MFMA32(pa, ones, lacc);
#pragma unroll
                    for (int dt = 0; dt < 2; dt++) {
                        int dd = dt * 32 + (l & 31);
                        int L = dd * 128 + ((kc * 16 + (l >> 5) * 8) * 2 ^ ((dd & 7) << 4));
                        bf16x8 vbf = *(const bf16x8*)((const char*)lV[cur] + L);
                        oacc[dt] = MFMA32(pa, vbf, oacc[dt]);
                    }
                }
                __builtin_amdgcn_s_setprio(0);
            }
            __syncthreads();                         // drains STAGE; next buf ready
            cur ^= 1;
        }
        // ---- epilogue: O[tok][h*64+d] bf16 ----
#pragma unroll
        for (int r = 0; r < 16; r++) {
            int rq = (r & 3) + 8 * (r >> 2) + 4 * (l >> 5);
            int t = wrow + rq;
            float inv = 1.0f / lacc[r];
            size_t base = ((size_t)b * TT + t) * DM + h * HD;
#pragma unroll
            for (int dt = 0; dt < 2; dt++)
                O[base + dt * 32 + (l & 31)] = (bf16)(oacc[dt][r] * inv);
        }
    }
#undef STAGE_KV
}

extern "C" void kernel_launch(void* const* d_in, const int* in_sizes, int n_in,
                              void* d_out, int out_size, void* d_ws, size_t ws_size,
                              hipStream_t stream) {
    const float* x    = (const float*)d_in[0];
    const float* Wqkv = (const float*)d_in[1];
    const float* Wout = (const float*)d_in[2];
    float* out = (float*)d_out;

    char* ws = (char*)d_ws;
    size_t off = 0;
    auto alloc = [&](size_t bytes) {
        void* p = ws + off;
        off += (bytes + 255) & ~(size_t)255;
        return p;
    };
    bf16* xb    = (bf16*)alloc((size_t)TOK * DM * 2);
    bf16* wqkvt = (bf16*)alloc((size_t)NQKV * DM * 2);
    bf16* woutt = (bf16*)alloc((size_t)DM * DM * 2);
    bf16* qr    = (bf16*)alloc((size_t)TOK * DM * 2);
    bf16* kr    = (bf16*)alloc((size_t)TOK * DM * 2);
    bf16* vt    = (bf16*)alloc((size_t)TOK * DM * 2);
    bf16* ob    = (bf16*)alloc((size_t)TOK * DM * 2);
    float* ct   = (float*)alloc((size_t)TT * 32 * 4);
    float* st   = (float*)alloc((size_t)TT * 32 * 4);
    (void)ws_size; (void)in_sizes; (void)n_in; (void)out_size;

    k_cvt<<<TOK * DM / 4 / 256, 256, 0, stream>>>(x, xb, TOK * DM);
    k_transpose_cvt<<<dim3(NQKV / 64, DM / 64), 256, 0, stream>>>(Wqkv, wqkvt, DM, NQKV);
    k_transpose_cvt<<<dim3(DM / 64, DM / 64), 256, 0, stream>>>(Wout, woutt, DM, DM);
    k_rope_tab<<<TT * 32 / 256, 256, 0, stream>>>(ct, st);
    // Q scale folds 1/sqrt(64) * log2(e) so softmax runs in exp2 domain (applied in GEMM epilogue)
    k_gemm_bt<1><<<dim3(NQKV / 128, TOK / 128), 256, 0, stream>>>(
        xb, wqkvt, TOK, NQKV, DM, nullptr, qr, kr, vt,
        ct, st, 0.125f * 1.4426950408889634f);
    k_attn<<<dim3(8, BB * NH), 256, 0, stream>>>(qr, kr, vt, ob);
    k_gemm_bt<2><<<dim3(DM / 128, TOK / 128), 256, 0, stream>>>(
        ob, woutt, TOK, DM, DM, out, nullptr, nullptr, nullptr,
        nullptr, nullptr, 0.0f);
}